// Round 20
// baseline (471.713 us; speedup 1.0000x reference)
//
#include <hip/hip_runtime.h>
#include <cstdint>
#include <cstddef>

#define NB 16384
#define NA 8
#define NE 512
#define NK 1024   // 2E
#define NN 4096   // A*E

typedef __bf16 bf16x8 __attribute__((ext_vector_type(8)));
typedef float  f32x4  __attribute__((ext_vector_type(4)));
typedef uint16_t u16x8 __attribute__((ext_vector_type(8)));
typedef uint32_t u32x4 __attribute__((ext_vector_type(4)));

__device__ __forceinline__ uint16_t cvt_bf16(float f) {
    uint32_t u = __builtin_bit_cast(uint32_t, f);
    u += 0x7fffu + ((u >> 16) & 1u);
    return (uint16_t)(u >> 16);
}

// legacy BK=32 chunk swizzle (k_prep only)
__device__ __forceinline__ int swz(int row) { return (row ^ (row >> 2)) & 3; }

// conflict-free BK=32 bf16 tile position (16B units): proven 0-conflict R5..R19
__device__ __forceinline__ int cf_pos(int row, int c) {
    return ((row >> 1) << 3) + ((((row & 1) << 2) + c) ^ ((row >> 1) & 7));
}

__device__ __forceinline__ void gl_lds16(const void* g, void* l) {
    __builtin_amdgcn_global_load_lds(
        (__attribute__((address_space(1))) void*)(void*)g,
        (__attribute__((address_space(3))) void*)l, 16, 0, 0);
}

// pack two f32 dwords -> bf16x2 dword, round-to-nearest (no tie-even)
__device__ __forceinline__ uint32_t pk2(uint32_t x, uint32_t y) {
    return ((x + 0x8000u) >> 16) | ((y + 0x8000u) & 0xffff0000u);
}

// ---- prep: lw/fwd/bwd transpose-cvt + bvec (no img/edge work at all) ----
__device__ __forceinline__ void tcvt_tile(const float* __restrict__ src,
                                          uint16_t* __restrict__ dst,
                                          int R, int C, int c0, int r0, int t) {
    __shared__ float tile[32][33];
    int tx = t & 31, ty = t >> 5;
#pragma unroll
    for (int yy = 0; yy < 4; ++yy) {
        int r = ty + yy * 8;
        tile[r][tx] = src[(size_t)(r0 + r) * C + c0 + tx];
    }
    __syncthreads();
#pragma unroll
    for (int yy = 0; yy < 4; ++yy) {
        int c = ty + yy * 8;
        dst[(size_t)(c0 + c) * R + r0 + tx] = cvt_bf16(tile[tx][c]);
    }
}

__global__ __launch_bounds__(256) void k_pre(const float* __restrict__ lw,
                                             const float* __restrict__ fwd,
                                             const float* __restrict__ bwd,
                                             const float* __restrict__ lb,
                                             uint16_t* __restrict__ lwT,
                                             uint16_t* __restrict__ fwdT,
                                             uint16_t* __restrict__ bwdT,
                                             float* __restrict__ bvec) {
    int b = blockIdx.x, t = threadIdx.x;
    if (b < 512) {
        int bx = b & 31, by = b >> 5;
        tcvt_tile(lw, lwT, NE, NK, bx * 32, by * 32, t);
    } else if (b < 2560) {
        int i = b - 512;
        int mat = i >> 8, bx = i & 15, by = (i >> 4) & 15;
        tcvt_tile(fwd + (size_t)mat * NE * NE, fwdT + (size_t)mat * NE * NE,
                  NE, NE, bx * 32, by * 32, t);
    } else if (b < 4608) {
        int i = b - 2560;
        int mat = i >> 8, bx = i & 15, by = (i >> 4) & 15;
        tcvt_tile(bwd + (size_t)mat * NE * NE, bwdT + (size_t)mat * NE * NE,
                  NE, NE, bx * 32, by * 32, t);
    } else {
        int i = b - 4608;
        int a = i >> 4, i0 = (i & 15) * 32;
        float s0 = 0.f, s1 = 0.f;
#pragma unroll 4
        for (int k = 0; k < 32; ++k) {
            float w = lb[i0 + k];
            const float* f = fwd + ((size_t)a * NE + i0 + k) * NE;
            s0 = fmaf(w, f[t], s0);
            s1 = fmaf(w, f[t + 256], s1);
        }
        atomicAdd(&bvec[a * NE + t], s0);
        atomicAdd(&bvec[a * NE + t + 256], s1);
    }
}

// TM[m=k'(1024)][n=(a,j)(4096)] = sum_i lwT[m][i]*fwdT[n][i]; store TMT[n][m] bf16
__global__ __launch_bounds__(256) void k_prep(const uint16_t* __restrict__ lwT,
                                              const uint16_t* __restrict__ fwdT,
                                              uint16_t* __restrict__ TMT) {
    __shared__ alignas(16) uint16_t lA[128 * 32];
    __shared__ alignas(16) uint16_t lB[128 * 32];
    int bz = blockIdx.x;
    int nt = bz & 31, mt = bz >> 5;
    int m0 = mt * 128, n0 = nt * 128;
    int t = threadIdx.x, lane = t & 63;
    int w = t >> 6, wm = w >> 1, wn = w & 1;
    int lr = lane & 15, lc = lane >> 4;
    int sl = swz(lr);
    f32x4 acc[4][4] = {};
    for (int k0 = 0; k0 < NE; k0 += 32) {
        __syncthreads();
#pragma unroll
        for (int p = 0; p < 2; ++p) {
            int idx = p * 256 + t;
            int row = idx >> 2, c16 = (idx & 3) ^ swz(row);
            gl_lds16(lwT + (size_t)(m0 + row) * NE + k0 + c16 * 8, lA + idx * 8);
            gl_lds16(fwdT + (size_t)(n0 + row) * NE + k0 + c16 * 8, lB + idx * 8);
        }
        __syncthreads();
        bf16x8 af[4], bfr[4];
#pragma unroll
        for (int i = 0; i < 4; ++i)
            af[i] = *(const bf16x8*)&lA[(wm * 64 + i * 16 + lr) * 32 + ((lc ^ sl) << 3)];
#pragma unroll
        for (int j = 0; j < 4; ++j)
            bfr[j] = *(const bf16x8*)&lB[(wn * 64 + j * 16 + lr) * 32 + ((lc ^ sl) << 3)];
#pragma unroll
        for (int i = 0; i < 4; ++i)
#pragma unroll
            for (int j = 0; j < 4; ++j)
                acc[i][j] = __builtin_amdgcn_mfma_f32_16x16x32_bf16(af[i], bfr[j], acc[i][j], 0, 0, 0);
    }
#pragma unroll
    for (int i = 0; i < 4; ++i) {
        int mb = m0 + wm * 64 + i * 16 + lc * 4;
#pragma unroll
        for (int j = 0; j < 4; ++j) {
            int n = n0 + wn * 64 + j * 16 + lr;
            ushort4 v;
            v.x = cvt_bf16(acc[i][j][0]);
            v.y = cvt_bf16(acc[i][j][1]);
            v.z = cvt_bf16(acc[i][j][2]);
            v.w = cvt_bf16(acc[i][j][3]);
            *(ushort4*)&TMT[(size_t)n * NK + mb] = v;
        }
    }
}

// attr GEMM: tri-buffer counted-vmcnt, A staged as RAW F32 via gl_lds
// (img tiles 0-15, edge tiles 16-31 — no conversion pass, no imgb),
// f32->bf16 pack at fragment read. BM=128 BN=512 BK=32, 1024 thr / 16
// waves (4x4, wave 32x128), a=XCD, LDS 144 KB (3 x (16KB A-f32 + 32KB B)).
// Ledger: 3 gl_lds/thread/tile (A:1, B:2); prologue 3 tiles (9 ops);
// steady vmcnt(6); tail 6,3,0.
template<bool WB>
__global__ __launch_bounds__(1024) void k_mm13(const float* __restrict__ img,
                                               const float* __restrict__ edge,
                                               const uint16_t* __restrict__ TMT,
                                               const float* __restrict__ bvec,
                                               float* __restrict__ attr,
                                               uint16_t* __restrict__ attrb) {
    __shared__ alignas(16) float    lAf[3][128 * 32];   // 3 x 16 KB (f32)
    __shared__ alignas(16) uint16_t lB[3][512 * 32];    // 3 x 32 KB (bf16)
    int o = blockIdx.x;             // 1024 = 8 xcd * 128 mt
    int a = o & 7, mt = o >> 3;
    int m0 = mt * 128;
    int t = threadIdx.x, lane = t & 63;
    int w = t >> 6, wm = w >> 2, wn = w & 3;   // wave: rows wm*32, cols wn*128
    int lr = lane & 15, lc = lane >> 4;
    // A stage map (1 unit/thread): unit t -> row=t>>3, chunk=(t&7)^(row&7) of 4 f32
    int rA = t >> 3, cA = (t & 7) ^ (rA & 7);
    // B stage map (2 units/thread), inverse cf_pos
    int srB[2], scB[2];
#pragma unroll
    for (int p = 0; p < 2; ++p) {
        int u = t + p * 1024;
        int rp = u >> 3, q = (u & 7) ^ (rp & 7);
        srB[p] = (rp << 1) | (q >> 2);
        scB[p] = (q & 3) << 3;
    }
    int arow[2], ac0[2];
#pragma unroll
    for (int i = 0; i < 2; ++i) {
        arow[i] = wm * 32 + i * 16 + lr;
        ac0[i] = (arow[i] * 8 + ((2 * lc) ^ (arow[i] & 7))) * 4;   // f32 index of chunk0
    }
    int boff[8];
#pragma unroll
    for (int j = 0; j < 8; ++j)
        boff[j] = cf_pos(wn * 128 + j * 16 + lr, lc) * 8;

    f32x4 acc[2][8] = {};

    auto stage = [&](int buf, int kt) {
        const float* srcA = (kt < 16)
            ? img + (size_t)(m0 + rA) * NE + kt * 32 + cA * 4
            : edge + ((size_t)(m0 + rA) * NA + a) * NE + (kt - 16) * 32 + cA * 4;
        gl_lds16(srcA, &lAf[buf][t * 4]);
#pragma unroll
        for (int p = 0; p < 2; ++p)
            gl_lds16(TMT + (size_t)(a * NE + srB[p]) * NK + kt * 32 + scB[p],
                     &lB[buf][(t + p * 1024) * 8]);
    };
    auto compute = [&](int cur) {
        bf16x8 af[2], bfr[8];
#pragma unroll
        for (int i = 0; i < 2; ++i) {
            u32x4 lo = *(const u32x4*)&lAf[cur][ac0[i]];
            u32x4 hi = *(const u32x4*)&lAf[cur][ac0[i] ^ 4];   // chunk c^1 = +-4 floats
            u32x4 pw = {pk2(lo[0], lo[1]), pk2(lo[2], lo[3]),
                        pk2(hi[0], hi[1]), pk2(hi[2], hi[3])};
            af[i] = __builtin_bit_cast(bf16x8, pw);
        }
#pragma unroll
        for (int j = 0; j < 8; ++j)
            bfr[j] = *(const bf16x8*)&lB[cur][boff[j]];
        asm volatile("s_waitcnt lgkmcnt(0)" ::: "memory");
        __builtin_amdgcn_sched_barrier(0);
#pragma unroll
        for (int i = 0; i < 2; ++i)
#pragma unroll
            for (int j = 0; j < 8; ++j)
                acc[i][j] = __builtin_amdgcn_mfma_f32_16x16x32_bf16(af[i], bfr[j], acc[i][j], 0, 0, 0);
    };

    stage(0, 0);
    stage(1, 1);
    stage(2, 2);
    for (int k = 0; k < 29; ++k) {
        int cur = k % 3;
        asm volatile("s_waitcnt vmcnt(6)\n\ts_barrier" ::: "memory");
        compute(cur);
        asm volatile("s_barrier" ::: "memory");
        stage(cur, k + 3);
    }
    asm volatile("s_waitcnt vmcnt(6)\n\ts_barrier" ::: "memory");
    compute(2);   // k=29
    asm volatile("s_barrier" ::: "memory");
    asm volatile("s_waitcnt vmcnt(3)\n\ts_barrier" ::: "memory");
    compute(0);   // k=30
    asm volatile("s_barrier" ::: "memory");
    asm volatile("s_waitcnt vmcnt(0)\n\ts_barrier" ::: "memory");
    compute(1);   // k=31

#pragma unroll
    for (int j = 0; j < 8; ++j) {
        float bv = bvec[a * NE + wn * 128 + j * 16 + lr];
#pragma unroll
        for (int i = 0; i < 2; ++i)
#pragma unroll
            for (int r = 0; r < 4; ++r)
                acc[i][j][r] += bv;
    }
#pragma unroll
    for (int i = 0; i < 2; ++i) {
#pragma unroll
        for (int r = 0; r < 4; ++r) {
            int bm = m0 + wm * 32 + i * 16 + lc * 4 + r;
            float* orow = attr + ((size_t)bm * NA + a) * NE;
#pragma unroll
            for (int j = 0; j < 8; ++j)
                __builtin_nontemporal_store(acc[i][j][r], &orow[wn * 128 + j * 16 + lr]);
            if (WB) {
                uint16_t* brw = attrb + ((size_t)bm * NA + a) * NE;
#pragma unroll
                for (int j = 0; j < 8; ++j)
                    brw[wn * 128 + j * 16 + lr] = cvt_bf16(acc[i][j][r]);
            }
        }
    }
}

// ind GEMM: tri-buffer counted-vmcnt (R17, passed). BM=128 BN=256 BK=64.
__global__ __launch_bounds__(512) void k_ind6(const uint16_t* __restrict__ attrb,
                                              const uint16_t* __restrict__ bwdT,
                                              const float* __restrict__ sw,
                                              float* __restrict__ ind) {
    __shared__ alignas(16) uint16_t lA[3][128 * 64];   // 3 x 16 KB
    __shared__ alignas(16) uint16_t lB[3][256 * 64];   // 3 x 32 KB
    int o = blockIdx.x;             // 512 = 64 * 8
    int xcd = o & 7;
    int jt = xcd & 1, ah = (xcd >> 1) & 1, mtl = xcd >> 2;
    int mt = ((o >> 3) << 1) | mtl;
    int m0 = mt * 128, jb = jt * 256, a0 = ah * 4;
    int t = threadIdx.x, lane = t & 63;
    int w = t >> 6, wm = w >> 2, wn = w & 3;
    int lr = lane & 15, lc = lane >> 4;
    int srA[2], scA[2];
#pragma unroll
    for (int p = 0; p < 2; ++p) {
        int u = t + p * 512;
        srA[p] = u >> 3;
        scA[p] = ((u & 7) ^ (srA[p] & 7)) << 3;
    }
    int srB[4], scB[4];
#pragma unroll
    for (int p = 0; p < 4; ++p) {
        int u = t + p * 512;
        srB[p] = u >> 3;
        scB[p] = ((u & 7) ^ (srB[p] & 7)) << 3;
    }
    int arow[4], brow[4];
#pragma unroll
    for (int i = 0; i < 4; ++i) {
        arow[i] = wm * 64 + i * 16 + lr;
        brow[i] = wn * 64 + i * 16 + lr;
    }
    float w0 = sw[a0], w1 = sw[a0 + 1], w2 = sw[a0 + 2], w3 = sw[a0 + 3];
    asm volatile("s_waitcnt vmcnt(0) lgkmcnt(0)" ::: "memory");

    f32x4 acc[4][4] = {};
    f32x4 res[4][4] = {};

    auto stage = [&](int buf, int kt) {
        int aa = a0 + (kt >> 3), kk = (kt & 7) * 64;
#pragma unroll
        for (int p = 0; p < 2; ++p)
            gl_lds16(attrb + ((size_t)(m0 + srA[p]) * NA + aa) * NE + kk + scA[p],
                     &lA[buf][(t + p * 512) * 8]);
#pragma unroll
        for (int p = 0; p < 4; ++p)
            gl_lds16(bwdT + ((size_t)aa * NE + jb + srB[p]) * NE + kk + scB[p],
                     &lB[buf][(t + p * 512) * 8]);
    };
    auto compute = [&](int cur) {
        bf16x8 af[4][2], bfr[4][2];
#pragma unroll
        for (int i = 0; i < 4; ++i)
#pragma unroll
            for (int h = 0; h < 2; ++h)
                af[i][h] = *(const bf16x8*)&lA[cur][(arow[i] << 6) + ((((h << 2) + lc) ^ (arow[i] & 7)) << 3)];
#pragma unroll
        for (int j = 0; j < 4; ++j)
#pragma unroll
            for (int h = 0; h < 2; ++h)
                bfr[j][h] = *(const bf16x8*)&lB[cur][(brow[j] << 6) + ((((h << 2) + lc) ^ (brow[j] & 7)) << 3)];
        asm volatile("s_waitcnt lgkmcnt(0)" ::: "memory");
        __builtin_amdgcn_sched_barrier(0);
#pragma unroll
        for (int h = 0; h < 2; ++h)
#pragma unroll
            for (int i = 0; i < 4; ++i)
#pragma unroll
                for (int j = 0; j < 4; ++j)
                    acc[i][j] = __builtin_amdgcn_mfma_f32_16x16x32_bf16(af[i][h], bfr[j][h], acc[i][j], 0, 0, 0);
    };
    auto finish_a = [&](int q) {
        float wa = (q == 0) ? w0 : (q == 1) ? w1 : (q == 2) ? w2 : w3;
#pragma unroll
        for (int i = 0; i < 4; ++i)
#pragma unroll
            for (int j = 0; j < 4; ++j) {
#pragma unroll
                for (int r = 0; r < 4; ++r)
                    res[i][j][r] += wa * fmaxf(acc[i][j][r], 0.f);
                acc[i][j] = (f32x4){0.f, 0.f, 0.f, 0.f};
            }
    };

    stage(0, 0);
    stage(1, 1);
    stage(2, 2);
    for (int k = 0; k < 30; ++k) {
        int cur = k % 3;
        asm volatile("s_waitcnt vmcnt(12)\n\ts_barrier" ::: "memory");
        compute(cur);
        if ((k & 7) == 7) finish_a(k >> 3);
        asm volatile("s_barrier" ::: "memory");
        if (k < 29) stage(cur, k + 3);
    }
    asm volatile("s_waitcnt vmcnt(6)\n\ts_barrier" ::: "memory");
    compute(0);
    asm volatile("s_barrier" ::: "memory");
    asm volatile("s_waitcnt vmcnt(0)\n\ts_barrier" ::: "memory");
    compute(1);
    finish_a(3);

#pragma unroll
    for (int i = 0; i < 4; ++i) {
#pragma unroll
        for (int r = 0; r < 4; ++r) {
            int bm = m0 + wm * 64 + i * 16 + lc * 4 + r;
            float* orow = ind + (size_t)bm * NE + jb;
#pragma unroll
            for (int j = 0; j < 4; ++j)
                atomicAdd(&orow[wn * 64 + j * 16 + lr], res[i][j][r]);
        }
    }
}

// fallback ind GEMM (f32 attr path, R7 structure)
__global__ __launch_bounds__(256) void k_ind4f(const float* __restrict__ attrf,
                                               const uint16_t* __restrict__ bwdT,
                                               const float* __restrict__ sw,
                                               float* __restrict__ ind) {
    __shared__ alignas(16) uint16_t lA[2][128 * 32];
    __shared__ alignas(16) uint16_t lB[2][128 * 32];
    int o = blockIdx.x;
    int xcd = o & 7, mt = o >> 3;
    int jt = xcd >> 1, ah = xcd & 1;
    int m0 = mt * 128, jb = jt * 128, a0 = ah * 4;
    int t = threadIdx.x, lane = t & 63;
    int w = t >> 6, wm = w >> 1, wn = w & 1;
    int lr = lane & 15, lc = lane >> 4;
    int srow[2], sc8[2];
#pragma unroll
    for (int p = 0; p < 2; ++p) {
        int u = p * 256 + t;
        int rp = u >> 3, q = (u & 7) ^ (rp & 7);
        srow[p] = (rp << 1) | (q >> 2);
        sc8[p] = (q & 3) << 3;
    }
    int erow[2], ec[2], epos[2];
#pragma unroll
    for (int p = 0; p < 2; ++p) {
        int u = p * 256 + t;
        erow[p] = u >> 2; ec[p] = u & 3;
        epos[p] = cf_pos(erow[p], ec[p]) * 8;
    }
    int aoff[4], boff[4];
#pragma unroll
    for (int i = 0; i < 4; ++i) {
        aoff[i] = cf_pos(wm * 64 + i * 16 + lr, lc) * 8;
        boff[i] = cf_pos(wn * 64 + i * 16 + lr, lc) * 8;
    }
    auto stage = [&](int buf, int s) {
        int aa = a0 + (s >> 4), kk = (s & 15) * 32;
#pragma unroll
        for (int p = 0; p < 2; ++p) {
            const float* sp = attrf + ((size_t)(m0 + erow[p]) * NA + aa) * NE + kk + ec[p] * 8;
            float4 v0 = ((const float4*)sp)[0];
            float4 v1 = ((const float4*)sp)[1];
            u16x8 ov = {cvt_bf16(v0.x), cvt_bf16(v0.y), cvt_bf16(v0.z), cvt_bf16(v0.w),
                        cvt_bf16(v1.x), cvt_bf16(v1.y), cvt_bf16(v1.z), cvt_bf16(v1.w)};
            *(u16x8*)&lA[buf][epos[p]] = ov;
        }
#pragma unroll
        for (int p = 0; p < 2; ++p)
            gl_lds16(bwdT + (size_t)(aa * NE + jb + srow[p]) * NE + kk + sc8[p],
                     &lB[buf][(p * 256 + t) * 8]);
    };
    f32x4 res[4][4] = {};
    f32x4 acc[4][4] = {};
    stage(0, 0);
    for (int s = 0; s < 64; ++s) {
        int cur = s & 1;
        __syncthreads();
        if (s < 63) stage(cur ^ 1, s + 1);
        bf16x8 af[4], bfr[4];
#pragma unroll
        for (int i = 0; i < 4; ++i) af[i] = *(const bf16x8*)&lA[cur][aoff[i]];
#pragma unroll
        for (int j = 0; j < 4; ++j) bfr[j] = *(const bf16x8*)&lB[cur][boff[j]];
#pragma unroll
        for (int i = 0; i < 4; ++i)
#pragma unroll
            for (int j = 0; j < 4; ++j)
                acc[i][j] = __builtin_amdgcn_mfma_f32_16x16x32_bf16(af[i], bfr[j], acc[i][j], 0, 0, 0);
        if ((s & 15) == 15) {
            float wa = sw[a0 + (s >> 4)];
#pragma unroll
            for (int i = 0; i < 4; ++i)
#pragma unroll
                for (int j = 0; j < 4; ++j) {
#pragma unroll
                    for (int r = 0; r < 4; ++r)
                        res[i][j][r] += wa * fmaxf(acc[i][j][r], 0.f);
                    acc[i][j] = (f32x4){0.f, 0.f, 0.f, 0.f};
                }
        }
    }
#pragma unroll
    for (int i = 0; i < 4; ++i) {
#pragma unroll
        for (int r = 0; r < 4; ++r) {
            int bm = m0 + wm * 64 + i * 16 + lc * 4 + r;
            float* orow = ind + (size_t)bm * NE + jb;
#pragma unroll
            for (int j = 0; j < 4; ++j)
                atomicAdd(&orow[wn * 64 + j * 16 + lr], res[i][j][r]);
        }
    }
}

extern "C" void kernel_launch(void* const* d_in, const int* in_sizes, int n_in,
                              void* d_out, int out_size, void* d_ws, size_t ws_size,
                              hipStream_t stream) {
    (void)in_sizes; (void)n_in; (void)out_size;
    const float* img  = (const float*)d_in[0];
    const float* edge = (const float*)d_in[1];
    const float* lw   = (const float*)d_in[2];
    const float* lb   = (const float*)d_in[3];
    const float* fwd  = (const float*)d_in[4];
    const float* bwd  = (const float*)d_in[5];
    const float* sw   = (const float*)d_in[6];
    float* attr = (float*)d_out;
    float* ind  = attr + (size_t)NB * NA * NE;

    char* ws = (char*)d_ws;
    size_t off = 0;
    auto alloc = [&](size_t bytes) { void* p = ws + off; off += bytes; return p; };
    uint16_t* lwT  = (uint16_t*)alloc((size_t)NK * NE * 2);       // 1 MB
    uint16_t* fwdT = (uint16_t*)alloc((size_t)NA * NE * NE * 2);  // 4 MB
    uint16_t* bwdT = (uint16_t*)alloc((size_t)NA * NE * NE * 2);  // 4 MB
    uint16_t* TMT  = (uint16_t*)alloc((size_t)NN * NK * 2);       // 8 MB
    float*    bvec = (float*)alloc((size_t)NN * 4);               // 16 KB

    const size_t BIGB = (size_t)NB * NA * NE * 2;  // 128 MB
    bool has_attrb = ws_size >= off + BIGB;
    uint16_t* attrb = has_attrb ? (uint16_t*)alloc(BIGB) : (uint16_t*)0;

    hipMemsetAsync(bvec, 0, (size_t)NN * 4, stream);
    hipMemsetAsync(ind, 0, (size_t)NB * NE * 4, stream);

    k_pre<<<4736, 256, 0, stream>>>(lw, fwd, bwd, lb, lwT, fwdT, bwdT, bvec);
    k_prep<<<(NK / 128) * (NN / 128), 256, 0, stream>>>(lwT, fwdT, TMT);

    int mm_grid = 8 * (NB / 128);   // 1024 blocks of 1024 threads

    if (has_attrb) {
        k_mm13<true><<<mm_grid, 1024, 0, stream>>>(img, edge, TMT, bvec, attr, attrb);
        k_ind6<<<8 * (NB / 256), 512, 0, stream>>>(attrb, bwdT, sw, ind);
    } else {
        k_mm13<false><<<mm_grid, 1024, 0, stream>>>(img, edge, TMT, bvec, attr, attrb);
        int ind_grid = (NB / 128) * (NE / 128) * 2;
        k_ind4f<<<ind_grid, 256, 0, stream>>>(attr, bwdT, sw, ind);
    }
}

// Round 21
// 433.703 us; speedup vs baseline: 1.0876x; 1.0876x over previous
//
#include <hip/hip_runtime.h>
#include <cstdint>
#include <cstddef>

#define NB 16384
#define NA 8
#define NE 512
#define NK 1024   // 2E
#define NN 4096   // A*E

typedef __bf16 bf16x8 __attribute__((ext_vector_type(8)));
typedef float  f32x4  __attribute__((ext_vector_type(4)));
typedef uint16_t u16x8 __attribute__((ext_vector_type(8)));

__device__ __forceinline__ uint16_t cvt_bf16(float f) {
    uint32_t u = __builtin_bit_cast(uint32_t, f);
    u += 0x7fffu + ((u >> 16) & 1u);
    return (uint16_t)(u >> 16);
}

// legacy BK=32 chunk swizzle (k_prep only)
__device__ __forceinline__ int swz(int row) { return (row ^ (row >> 2)) & 3; }

// conflict-free BK=32 tile position (16B units): row-pair interleave + 3-bit XOR
// proven 0-conflict in R5..R15 PMC
__device__ __forceinline__ int cf_pos(int row, int c) {
    return ((row >> 1) << 3) + ((((row & 1) << 2) + c) ^ ((row >> 1) & 7));
}

__device__ __forceinline__ void gl_lds16(const void* g, void* l) {
    __builtin_amdgcn_global_load_lds(
        (__attribute__((address_space(1))) void*)(void*)g,
        (__attribute__((address_space(3))) void*)l, 16, 0, 0);
}

// ---- fused prep: lw/fwd/bwd transpose-cvt + img cvt + bvec, one launch ----
__device__ __forceinline__ void tcvt_tile(const float* __restrict__ src,
                                          uint16_t* __restrict__ dst,
                                          int R, int C, int c0, int r0, int t) {
    __shared__ float tile[32][33];
    int tx = t & 31, ty = t >> 5;
#pragma unroll
    for (int yy = 0; yy < 4; ++yy) {
        int r = ty + yy * 8;
        tile[r][tx] = src[(size_t)(r0 + r) * C + c0 + tx];
    }
    __syncthreads();
#pragma unroll
    for (int yy = 0; yy < 4; ++yy) {
        int c = ty + yy * 8;
        dst[(size_t)(c0 + c) * R + r0 + tx] = cvt_bf16(tile[tx][c]);
    }
}

__global__ __launch_bounds__(256) void k_pre(const float* __restrict__ lw,
                                             const float* __restrict__ fwd,
                                             const float* __restrict__ bwd,
                                             const float* __restrict__ img,
                                             const float* __restrict__ lb,
                                             uint16_t* __restrict__ lwT,
                                             uint16_t* __restrict__ fwdT,
                                             uint16_t* __restrict__ bwdT,
                                             uint16_t* __restrict__ imgb,
                                             float* __restrict__ bvec) {
    int b = blockIdx.x, t = threadIdx.x;
    if (b < 512) {
        int bx = b & 31, by = b >> 5;
        tcvt_tile(lw, lwT, NE, NK, bx * 32, by * 32, t);
    } else if (b < 2560) {
        int i = b - 512;
        int mat = i >> 8, bx = i & 15, by = (i >> 4) & 15;
        tcvt_tile(fwd + (size_t)mat * NE * NE, fwdT + (size_t)mat * NE * NE,
                  NE, NE, bx * 32, by * 32, t);
    } else if (b < 4608) {
        int i = b - 2560;
        int mat = i >> 8, bx = i & 15, by = (i >> 4) & 15;
        tcvt_tile(bwd + (size_t)mat * NE * NE, bwdT + (size_t)mat * NE * NE,
                  NE, NE, bx * 32, by * 32, t);
    } else if (b < 12800) {
        int i = (b - 4608) * 256 + t;
        float4 v = ((const float4*)img)[i];
        ushort4 o;
        o.x = cvt_bf16(v.x); o.y = cvt_bf16(v.y); o.z = cvt_bf16(v.z); o.w = cvt_bf16(v.w);
        ((ushort4*)imgb)[i] = o;
    } else {
        int i = b - 12800;
        int a = i >> 4, i0 = (i & 15) * 32;
        float s0 = 0.f, s1 = 0.f;
#pragma unroll 4
        for (int k = 0; k < 32; ++k) {
            float w = lb[i0 + k];
            const float* f = fwd + ((size_t)a * NE + i0 + k) * NE;
            s0 = fmaf(w, f[t], s0);
            s1 = fmaf(w, f[t + 256], s1);
        }
        atomicAdd(&bvec[a * NE + t], s0);
        atomicAdd(&bvec[a * NE + t + 256], s1);
    }
}

// TM[m=k'(1024)][n=(a,j)(4096)] = sum_i lwT[m][i]*fwdT[n][i]; store TMT[n][m] bf16
__global__ __launch_bounds__(256) void k_prep(const uint16_t* __restrict__ lwT,
                                              const uint16_t* __restrict__ fwdT,
                                              uint16_t* __restrict__ TMT) {
    __shared__ alignas(16) uint16_t lA[128 * 32];
    __shared__ alignas(16) uint16_t lB[128 * 32];
    int bz = blockIdx.x;
    int nt = bz & 31, mt = bz >> 5;
    int m0 = mt * 128, n0 = nt * 128;
    int t = threadIdx.x, lane = t & 63;
    int w = t >> 6, wm = w >> 1, wn = w & 1;
    int lr = lane & 15, lc = lane >> 4;
    int sl = swz(lr);
    f32x4 acc[4][4] = {};
    for (int k0 = 0; k0 < NE; k0 += 32) {
        __syncthreads();
#pragma unroll
        for (int p = 0; p < 2; ++p) {
            int idx = p * 256 + t;
            int row = idx >> 2, c16 = (idx & 3) ^ swz(row);
            gl_lds16(lwT + (size_t)(m0 + row) * NE + k0 + c16 * 8, lA + idx * 8);
            gl_lds16(fwdT + (size_t)(n0 + row) * NE + k0 + c16 * 8, lB + idx * 8);
        }
        __syncthreads();
        bf16x8 af[4], bfr[4];
#pragma unroll
        for (int i = 0; i < 4; ++i)
            af[i] = *(const bf16x8*)&lA[(wm * 64 + i * 16 + lr) * 32 + ((lc ^ sl) << 3)];
#pragma unroll
        for (int j = 0; j < 4; ++j)
            bfr[j] = *(const bf16x8*)&lB[(wn * 64 + j * 16 + lr) * 32 + ((lc ^ sl) << 3)];
#pragma unroll
        for (int i = 0; i < 4; ++i)
#pragma unroll
            for (int j = 0; j < 4; ++j)
                acc[i][j] = __builtin_amdgcn_mfma_f32_16x16x32_bf16(af[i], bfr[j], acc[i][j], 0, 0, 0);
    }
#pragma unroll
    for (int i = 0; i < 4; ++i) {
        int mb = m0 + wm * 64 + i * 16 + lc * 4;
#pragma unroll
        for (int j = 0; j < 4; ++j) {
            int n = n0 + wn * 64 + j * 16 + lr;
            ushort4 v;
            v.x = cvt_bf16(acc[i][j][0]);
            v.y = cvt_bf16(acc[i][j][1]);
            v.z = cvt_bf16(acc[i][j][2]);
            v.w = cvt_bf16(acc[i][j][3]);
            *(ushort4*)&TMT[(size_t)n * NK + mb] = v;
        }
    }
}

// attr[b,a,j] = img[b]@TM_a[0:512] + edge[b,a]@TM_a[512:1024] + bvec_a[j]
// 1024 thr / 16 waves (4x4), 128x512 tile (wave tile 32x128), BK=32 dbuf,
// cf_pos layout, a=XCD (one block covers ALL of a's N -> A staged once),
// T14 edge-f32 fuse on waves 0-7, nontemporal attr. LDS 80 KB -> 2 blocks/CU.
template<bool WB>
__global__ __launch_bounds__(1024) void k_mm9(const uint16_t* __restrict__ imgb,
                                              const float* __restrict__ edge,
                                              const uint16_t* __restrict__ TMT,
                                              const float* __restrict__ bvec,
                                              float* __restrict__ attr,
                                              uint16_t* __restrict__ attrb) {
    __shared__ alignas(16) uint16_t lA[2][128 * 32];   // 2 x 8 KB
    __shared__ alignas(16) uint16_t lB[2][512 * 32];   // 2 x 32 KB
    int o = blockIdx.x;             // 1024 = 8 xcd * 128 mt
    int a = o & 7, mt = o >> 3;
    int m0 = mt * 128;
    int t = threadIdx.x, lane = t & 63;
    int w = t >> 6, wm = w >> 2, wn = w & 3;   // wave tile: rows wm*32.., cols wn*128..
    int lr = lane & 15, lc = lane >> 4;
    // A stage map (waves 0-7, 1 unit/thread): inverse of cf_pos
    int rpA = t >> 3, qA = (t & 7) ^ (rpA & 7);
    int srA = (rpA << 1) | (qA >> 2), scA = (qA & 3) << 3;
    // B stage map (all threads, 2 units/thread)
    int srB[2], scB[2];
#pragma unroll
    for (int p = 0; p < 2; ++p) {
        int u = t + p * 1024;
        int rp = u >> 3, q = (u & 7) ^ (rp & 7);
        srB[p] = (rp << 1) | (q >> 2);
        scB[p] = (q & 3) << 3;
    }
    // edge f32 path (waves 0-7): thread owns (row, chunk) natural, writes swizzled
    int er = t >> 2, ec = t & 3;
    int epos = cf_pos(er, ec) * 8;
    int aoff[2], boff[8];
#pragma unroll
    for (int i = 0; i < 2; ++i)
        aoff[i] = cf_pos(wm * 32 + i * 16 + lr, lc) * 8;
#pragma unroll
    for (int j = 0; j < 8; ++j)
        boff[j] = cf_pos(wn * 128 + j * 16 + lr, lc) * 8;
    auto stage_img = [&](int buf, int s) {
        if (t < 512)
            gl_lds16(imgb + (size_t)(m0 + srA) * NE + s * 32 + scA, &lA[buf][t * 8]);
    };
    auto stage_tmt = [&](int buf, int s) {
#pragma unroll
        for (int p = 0; p < 2; ++p)
            gl_lds16(TMT + (size_t)(a * NE + srB[p]) * NK + s * 32 + scB[p],
                     &lB[buf][(t + p * 1024) * 8]);
    };
    f32x4 acc[2][8] = {};
    stage_img(0, 0);
    stage_tmt(0, 0);
    for (int s = 0; s < 32; ++s) {
        int cur = s & 1, nb = cur ^ 1;
        __syncthreads();
        float4 e0, e1;
        bool eN = (s < 31) && (s + 1 >= 16);
        if (s < 31) {
            if (s + 1 < 16) {
                stage_img(nb, s + 1);
            } else if (t < 512) {
                int kk = (s + 1 - 16) * 32;
                const float* sp = edge + ((size_t)(m0 + er) * NA + a) * NE + kk + ec * 8;
                e0 = ((const float4*)sp)[0];
                e1 = ((const float4*)sp)[1];
            }
            stage_tmt(nb, s + 1);
        }
        bf16x8 af[2], bfr[8];
#pragma unroll
        for (int i = 0; i < 2; ++i) af[i] = *(const bf16x8*)&lA[cur][aoff[i]];
#pragma unroll
        for (int j = 0; j < 8; ++j) bfr[j] = *(const bf16x8*)&lB[cur][boff[j]];
#pragma unroll
        for (int i = 0; i < 2; ++i)
#pragma unroll
            for (int j = 0; j < 8; ++j)
                acc[i][j] = __builtin_amdgcn_mfma_f32_16x16x32_bf16(af[i], bfr[j], acc[i][j], 0, 0, 0);
        if (eN && t < 512) {
            u16x8 ov = {cvt_bf16(e0.x), cvt_bf16(e0.y), cvt_bf16(e0.z), cvt_bf16(e0.w),
                        cvt_bf16(e1.x), cvt_bf16(e1.y), cvt_bf16(e1.z), cvt_bf16(e1.w)};
            *(u16x8*)&lA[nb][epos] = ov;
        }
    }
#pragma unroll
    for (int j = 0; j < 8; ++j) {
        float bv = bvec[a * NE + wn * 128 + j * 16 + lr];
#pragma unroll
        for (int i = 0; i < 2; ++i)
#pragma unroll
            for (int r = 0; r < 4; ++r)
                acc[i][j][r] += bv;
    }
#pragma unroll
    for (int i = 0; i < 2; ++i) {
#pragma unroll
        for (int r = 0; r < 4; ++r) {
            int bm = m0 + wm * 32 + i * 16 + lc * 4 + r;
            float* orow = attr + ((size_t)bm * NA + a) * NE;
#pragma unroll
            for (int j = 0; j < 8; ++j)
                __builtin_nontemporal_store(acc[i][j][r], &orow[wn * 128 + j * 16 + lr]);
            if (WB) {
                uint16_t* brw = attrb + ((size_t)bm * NA + a) * NE;
#pragma unroll
                for (int j = 0; j < 8; ++j)
                    brw[wn * 128 + j * 16 + lr] = cvt_bf16(acc[i][j][r]);
            }
        }
    }
}

// ind[b,j] += sum_{a in half} sw[a]*relu(attrb[b,a,:]@bwd_a[:,j])
// R7/R12/R15 winner verbatim: 256 thr, 128x128, BK=32 dbuf, cf_pos,
// (jt,ah)=XCD, a-split-2 atomics.
template<bool AB>
__global__ __launch_bounds__(256) void k_ind4(const float* __restrict__ attrf,
                                              const uint16_t* __restrict__ attrb,
                                              const uint16_t* __restrict__ bwdT,
                                              const float* __restrict__ sw,
                                              float* __restrict__ ind) {
    __shared__ alignas(16) uint16_t lA[2][128 * 32];
    __shared__ alignas(16) uint16_t lB[2][128 * 32];
    int o = blockIdx.x;            // 1024 = 8 xcd * 128 mt
    int xcd = o & 7, mt = o >> 3;
    int jt = xcd >> 1, ah = xcd & 1;
    int m0 = mt * 128, jb = jt * 128, a0 = ah * 4;
    int t = threadIdx.x, lane = t & 63;
    int w = t >> 6, wm = w >> 1, wn = w & 1;
    int lr = lane & 15, lc = lane >> 4;
    int srow[2], sc8[2];
#pragma unroll
    for (int p = 0; p < 2; ++p) {
        int u = p * 256 + t;
        int rp = u >> 3, q = (u & 7) ^ (rp & 7);
        srow[p] = (rp << 1) | (q >> 2);
        sc8[p] = (q & 3) << 3;
    }
    int erow[2], ec[2], epos[2];
#pragma unroll
    for (int p = 0; p < 2; ++p) {
        int u = p * 256 + t;
        erow[p] = u >> 2; ec[p] = u & 3;
        epos[p] = cf_pos(erow[p], ec[p]) * 8;
    }
    int aoff[4], boff[4];
#pragma unroll
    for (int i = 0; i < 4; ++i) {
        aoff[i] = cf_pos(wm * 64 + i * 16 + lr, lc) * 8;
        boff[i] = cf_pos(wn * 64 + i * 16 + lr, lc) * 8;
    }
    auto stage = [&](int buf, int s) {
        int aa = a0 + (s >> 4), kk = (s & 15) * 32;
        if (AB) {
#pragma unroll
            for (int p = 0; p < 2; ++p)
                gl_lds16(attrb + ((size_t)(m0 + srow[p]) * NA + aa) * NE + kk + sc8[p],
                         &lA[buf][(p * 256 + t) * 8]);
        } else {
#pragma unroll
            for (int p = 0; p < 2; ++p) {
                const float* sp = attrf + ((size_t)(m0 + erow[p]) * NA + aa) * NE + kk + ec[p] * 8;
                float4 v0 = ((const float4*)sp)[0];
                float4 v1 = ((const float4*)sp)[1];
                u16x8 ov = {cvt_bf16(v0.x), cvt_bf16(v0.y), cvt_bf16(v0.z), cvt_bf16(v0.w),
                            cvt_bf16(v1.x), cvt_bf16(v1.y), cvt_bf16(v1.z), cvt_bf16(v1.w)};
                *(u16x8*)&lA[buf][epos[p]] = ov;
            }
        }
#pragma unroll
        for (int p = 0; p < 2; ++p)
            gl_lds16(bwdT + (size_t)(aa * NE + jb + srow[p]) * NE + kk + sc8[p],
                     &lB[buf][(p * 256 + t) * 8]);
    };
    f32x4 res[4][4] = {};
    f32x4 acc[4][4] = {};
    stage(0, 0);
    for (int s = 0; s < 64; ++s) {
        int cur = s & 1;
        __syncthreads();
        if (s < 63) stage(cur ^ 1, s + 1);
        bf16x8 af[4], bfr[4];
#pragma unroll
        for (int i = 0; i < 4; ++i) af[i] = *(const bf16x8*)&lA[cur][aoff[i]];
#pragma unroll
        for (int j = 0; j < 4; ++j) bfr[j] = *(const bf16x8*)&lB[cur][boff[j]];
#pragma unroll
        for (int i = 0; i < 4; ++i)
#pragma unroll
            for (int j = 0; j < 4; ++j)
                acc[i][j] = __builtin_amdgcn_mfma_f32_16x16x32_bf16(af[i], bfr[j], acc[i][j], 0, 0, 0);
        if ((s & 15) == 15) {
            float wa = sw[a0 + (s >> 4)];
#pragma unroll
            for (int i = 0; i < 4; ++i)
#pragma unroll
                for (int j = 0; j < 4; ++j) {
#pragma unroll
                    for (int r = 0; r < 4; ++r)
                        res[i][j][r] += wa * fmaxf(acc[i][j][r], 0.f);
                    acc[i][j] = (f32x4){0.f, 0.f, 0.f, 0.f};
                }
        }
    }
#pragma unroll
    for (int i = 0; i < 4; ++i) {
#pragma unroll
        for (int r = 0; r < 4; ++r) {
            int bm = m0 + wm * 64 + i * 16 + lc * 4 + r;
            float* orow = ind + (size_t)bm * NE + jb;
#pragma unroll
            for (int j = 0; j < 4; ++j)
                atomicAdd(&orow[wn * 64 + j * 16 + lr], res[i][j][r]);
        }
    }
}

extern "C" void kernel_launch(void* const* d_in, const int* in_sizes, int n_in,
                              void* d_out, int out_size, void* d_ws, size_t ws_size,
                              hipStream_t stream) {
    (void)in_sizes; (void)n_in; (void)out_size;
    const float* img  = (const float*)d_in[0];
    const float* edge = (const float*)d_in[1];
    const float* lw   = (const float*)d_in[2];
    const float* lb   = (const float*)d_in[3];
    const float* fwd  = (const float*)d_in[4];
    const float* bwd  = (const float*)d_in[5];
    const float* sw   = (const float*)d_in[6];
    float* attr = (float*)d_out;
    float* ind  = attr + (size_t)NB * NA * NE;

    char* ws = (char*)d_ws;
    size_t off = 0;
    auto alloc = [&](size_t bytes) { void* p = ws + off; off += bytes; return p; };
    uint16_t* lwT  = (uint16_t*)alloc((size_t)NK * NE * 2);       // 1 MB
    uint16_t* fwdT = (uint16_t*)alloc((size_t)NA * NE * NE * 2);  // 4 MB
    uint16_t* bwdT = (uint16_t*)alloc((size_t)NA * NE * NE * 2);  // 4 MB
    uint16_t* TMT  = (uint16_t*)alloc((size_t)NN * NK * 2);       // 8 MB
    uint16_t* imgb = (uint16_t*)alloc((size_t)NB * NE * 2);       // 16 MB
    float*    bvec = (float*)alloc((size_t)NN * 4);               // 16 KB

    const size_t BIGB = (size_t)NB * NA * NE * 2;  // 128 MB
    bool has_attrb = ws_size >= off + BIGB;
    uint16_t* attrb = has_attrb ? (uint16_t*)alloc(BIGB) : (uint16_t*)0;

    hipMemsetAsync(bvec, 0, (size_t)NN * 4, stream);
    hipMemsetAsync(ind, 0, (size_t)NB * NE * 4, stream);

    k_pre<<<12928, 256, 0, stream>>>(lw, fwd, bwd, img, lb, lwT, fwdT, bwdT, imgb, bvec);
    k_prep<<<(NK / 128) * (NN / 128), 256, 0, stream>>>(lwT, fwdT, TMT);

    int mm_grid = 8 * (NB / 128);                // 1024 blocks of 1024 threads
    int ind_grid = (NB / 128) * (NE / 128) * 2;  // 1024 blocks of 256 threads

    if (has_attrb) {
        k_mm9<true><<<mm_grid, 1024, 0, stream>>>(imgb, edge, TMT, bvec, attr, attrb);
        k_ind4<true><<<ind_grid, 256, 0, stream>>>(attr, attrb, bwdT, sw, ind);
    } else {
        k_mm9<false><<<mm_grid, 1024, 0, stream>>>(imgb, edge, TMT, bvec, attr, attrb);
        k_ind4<false><<<ind_grid, 256, 0, stream>>>(attr, attrb, bwdT, sw, ind);
    }
}